// Round 23
// baseline (54.816 us; speedup 1.0000x reference)
//
#include <hip/hip_runtime.h>
#include <hip/hip_bf16.h>

#define NB 4096
#define NGRP 256                 // NB/16 batch groups
#define MESH 778
#define NPP 3136                 // padded N: 4 rows (x,y,z,pad) per vertex
#define JOUT (NB*MESH*3)
#define PI_F 3.14159265358979323846f

// ws layout (float offsets).
// Bh fragment-major u16 (hi only); Ah/Al fragment-major u16 (pose rows, split).
// T16h u16 (hi only): [g][col=i16*12+e][k=j(0..15), pad 16..31].
// Pw f32 [160 k][NB]; Af f32 [192 e][NB] (Rot-folded).
#define F_JS   0
#define F_PW   528
#define F_AF   (F_PW + 160*NB)
#define F_AH   (F_AF + 192*NB)
#define F_AL   (F_AH + 80*NB)
#define F_BTH  (F_AL + 80*NB)
#define F_BTL  (F_BTH + NPP*80)          // unused (layout stability)
#define F_T16H (F_BTL + NPP*80)
#define F_T16L (F_T16H + NGRP*3072)      // unused
#define WS_NEED_BYTES ((size_t)(F_T16L + NGRP*3072 + 64) * 4)

typedef __attribute__((ext_vector_type(8))) short short8;
typedef __attribute__((ext_vector_type(4))) float f32x4;

__device__ __forceinline__ unsigned short rne_bf16(float x){
  unsigned u = __float_as_uint(x);
  return (unsigned short)((u + 0x7FFFu + ((u>>16)&1u)) >> 16);
}
__device__ __forceinline__ float bf16f(unsigned short h){
  return __uint_as_float(((unsigned)h)<<16);
}

__device__ __forceinline__ void rodrigues(float x, float y, float z, float* R){
  float t2 = x*x + y*y + z*z;
  float th = sqrtf(t2);
  if (th < 1e-30f){
    float a = 1.0f - t2*(1.0f/6.0f);
    float b = 0.5f - t2*(1.0f/24.0f);
    R[0] = 1.0f + b*(x*x - t2); R[1] = -a*z + b*x*y;       R[2] = a*y + b*x*z;
    R[3] = a*z + b*x*y;         R[4] = 1.0f + b*(y*y - t2); R[5] = -a*x + b*y*z;
    R[6] = -a*y + b*x*z;        R[7] = a*x + b*y*z;        R[8] = 1.0f + b*(z*z - t2);
  } else {
    float inv = 1.0f / fmaxf(th, 1e-12f);
    float nx = x*inv, ny = y*inv, nz = z*inv;
    float s = sinf(th), c = cosf(th), ic = 1.0f - c;
    R[0] = c + ic*nx*nx;    R[1] = ic*nx*ny - s*nz; R[2] = ic*nx*nz + s*ny;
    R[3] = ic*ny*nx + s*nz; R[4] = c + ic*ny*ny;    R[5] = ic*ny*nz - s*nx;
    R[6] = ic*nz*nx - s*ny; R[7] = ic*nz*ny + s*nx; R[8] = c + ic*nz*nz;
  }
}

// ---- kJP: wide kJ (blocks 0..527, one (j,combo) each) + B^T-hi build (blocks 528..)
__global__ __launch_bounds__(256) void kJP(const float* __restrict__ vt,
    const float* __restrict__ sd, const float* __restrict__ pd,
    const float* __restrict__ jreg, float* __restrict__ ws){
  __shared__ float s_part[4];
  if (blockIdx.x < 528){
    int j = blockIdx.x / 33, combo = blockIdx.x - j*33;
    int c = combo / 11, k = combo - c*11;
    float acc = 0.f;
    for (int m = threadIdx.x; m < MESH; m += 256){
      float jr = jreg[j*MESH + m];
      float x = (k < 10) ? sd[(m*3 + c)*10 + k] : vt[m*3 + c];
      acc += jr * x;
    }
    #pragma unroll
    for (int off = 32; off; off >>= 1) acc += __shfl_down(acc, off, 64);
    int lane = threadIdx.x & 63, w = threadIdx.x >> 6;
    if (lane == 0) s_part[w] = acc;
    __syncthreads();
    if (threadIdx.x == 0)
      ws[j*33 + combo] = s_part[0]+s_part[1]+s_part[2]+s_part[3];
  } else {
    int idx = (blockIdx.x-528)*256 + threadIdx.x;
    if (idx >= NPP*160) return;
    int chunk = idx >> 9, q = idx & 511;
    int ln = q >> 3, e = q & 7;
    int tile = chunk/5, ks = chunk - tile*5;
    int c16 = ln & 15, kg = ln >> 4;
    int np = tile*16 + c16;
    int k  = ks*32 + kg*8 + e;
    int m = np >> 2, c = np & 3;
    float x = 0.f;
    if (c < 3 && m < MESH){
      int row = m*3 + c;
      if (k < 135) x = pd[(size_t)row*135 + k];
      else if (k < 145) x = sd[row*10 + (k-135)];
      else if (k == 145) x = vt[row];
    }
    ((unsigned short*)(ws + F_BTH))[idx] = rne_bf16(x);
  }
}

// ---- kB: chain-parallel pose pipeline; ALL writes coalesced f32 transposed.
__global__ __launch_bounds__(256) void kB(const float* __restrict__ root,
    const float* __restrict__ other, const float* __restrict__ bet,
    const float* __restrict__ hc, const float* __restrict__ hm,
    float* __restrict__ ws, float* __restrict__ out){
  int b = blockIdx.x*256 + threadIdx.x;
  if (b >= NB) return;
  int ch = blockIdx.y;
  float* Pw = ws + F_PW;
  float* Af = ws + F_AF;

  float o[6];
  #pragma unroll
  for (int u=0;u<6;++u) o[u] = other[b*6+u];
  float bt[10];
  #pragma unroll
  for (int k=0;k<10;++k) bt[k] = bet[b*10+k];
  float Rot[9];
  rodrigues(root[b*3+0], root[b*3+1], root[b*3+2], Rot);
  float R0[9];
  rodrigues(PI_F, 0.f, 0.f, R0);
  float J0[3];
  #pragma unroll
  for (int c=0;c<3;++c){
    float a = ws[c*11 + 10];
    #pragma unroll
    for (int k=0;k<10;++k) a += bt[k]*ws[c*11 + k];
    J0[c]=a;
  }
  if (ch == 0){
    #pragma unroll
    for (int k=135;k<160;++k)
      Pw[(size_t)k*NB + b] = (k < 145) ? bt[k-135] : (k == 145 ? 1.0f : 0.f);
    float tr0[3];
    #pragma unroll
    for (int r=0;r<3;++r){
      float tr = J0[r];
      #pragma unroll
      for (int d=0;d<3;++d) tr -= R0[r*3+d]*J0[d];
      tr0[r]=tr;
    }
    #pragma unroll
    for (int r=0;r<3;++r)
      #pragma unroll
      for (int cc=0;cc<4;++cc){
        float v = 0.f;
        #pragma unroll
        for (int d=0;d<3;++d) v += Rot[r*3+d]*((cc<3)? R0[d*3+cc] : tr0[d]);
        Af[(size_t)(r*4+cc)*NB + b] = v;
      }
    int base = JOUT + b*63;
    #pragma unroll
    for (int c=0;c<3;++c)
      out[base+c] = Rot[c*3+0]*J0[0]+Rot[c*3+1]*J0[1]+Rot[c*3+2]*J0[2];
  }
  float GpR[9], Gpt[3], Jp[3];
  #pragma unroll
  for (int e=0;e<9;++e) GpR[e]=R0[e];
  #pragma unroll
  for (int c=0;c<3;++c){ Gpt[c]=J0[c]; Jp[c]=J0[c]; }
  int start = 1 + ch*3;
  #pragma unroll 1
  for (int s=0;s<3;++s){
    int i = start+s;
    int q0 = (i-1)*3;
    float rx=hm[q0], ry=hm[q0+1], rz=hm[q0+2];
    #pragma unroll
    for (int u=0;u<6;++u){
      rx += o[u]*hc[u*45+q0+0];
      ry += o[u]*hc[u*45+q0+1];
      rz += o[u]*hc[u*45+q0+2];
    }
    float Rl[9]; rodrigues(rx,ry,rz,Rl);
    #pragma unroll
    for (int e=0;e<9;++e){
      float v = (e==0||e==4||e==8) ? Rl[e]-1.f : Rl[e];
      Pw[(size_t)((i-1)*9+e)*NB + b] = v;
    }
    float Ji[3];
    #pragma unroll
    for (int c=0;c<3;++c){
      float a = ws[i*33 + c*11 + 10];
      #pragma unroll
      for (int k=0;k<10;++k) a += bt[k]*ws[i*33 + c*11 + k];
      Ji[c]=a;
    }
    float tl[3] = {Ji[0]-Jp[0], Ji[1]-Jp[1], Ji[2]-Jp[2]};
    float GR[9], Gt[3];
    #pragma unroll
    for (int r=0;r<3;++r){
      #pragma unroll
      for (int cc=0;cc<3;++cc)
        GR[r*3+cc] = GpR[r*3+0]*Rl[0*3+cc] + GpR[r*3+1]*Rl[1*3+cc] + GpR[r*3+2]*Rl[2*3+cc];
      Gt[r] = Gpt[r] + GpR[r*3+0]*tl[0] + GpR[r*3+1]*tl[1] + GpR[r*3+2]*tl[2];
    }
    float trv[3];
    #pragma unroll
    for (int r=0;r<3;++r)
      trv[r] = Gt[r] - (GR[r*3+0]*Ji[0] + GR[r*3+1]*Ji[1] + GR[r*3+2]*Ji[2]);
    #pragma unroll
    for (int r=0;r<3;++r)
      #pragma unroll
      for (int cc=0;cc<4;++cc){
        float v = 0.f;
        #pragma unroll
        for (int d=0;d<3;++d) v += Rot[r*3+d]*((cc<3)? GR[d*3+cc] : trv[d]);
        Af[(size_t)(i*12 + r*4+cc)*NB + b] = v;
      }
    int gx = i + (i>=4) + (i>=7) + (i>=10) + (i>=13);
    int base = JOUT + b*63 + gx*3;
    #pragma unroll
    for (int c=0;c<3;++c)
      out[base+c] = Rot[c*3+0]*Gt[0]+Rot[c*3+1]*Gt[1]+Rot[c*3+2]*Gt[2];
    #pragma unroll
    for (int e=0;e<9;++e) GpR[e]=GR[e];
    #pragma unroll
    for (int c=0;c<3;++c){ Gpt[c]=Gt[c]; Jp[c]=Ji[c]; }
  }
}

// ---- kT: element-parallel converter (linear u16 writes).
__global__ __launch_bounds__(256) void kT(float* __restrict__ ws){
  int idx = blockIdx.x*256 + threadIdx.x;
  const float* Pw = ws + F_PW;
  const float* Af = ws + F_AF;
  if (idx < NB*160){
    int chunk = idx >> 9, q = idx & 511;
    int ln = q >> 3, e = q & 7;
    int tile = chunk/5, ks = chunk - tile*5;
    int c16 = ln & 15, kg = ln >> 4;
    int b = tile*16 + c16;
    int k = ks*32 + kg*8 + e;
    float x = Pw[(size_t)k*NB + b];
    unsigned short h = rne_bf16(x);
    ((unsigned short*)(ws + F_AH))[idx] = h;
    ((unsigned short*)(ws + F_AL))[idx] = rne_bf16(x - bf16f(h));
  } else {
    int i2 = idx - NB*160;
    if (i2 >= NGRP*6144) return;
    int g = i2/6144, r = i2 - g*6144;
    int col = r >> 5, k = r & 31;
    int i16 = col/12, e = col - i16*12;
    int b = g*16 + i16;
    float x = (k < 16) ? Af[(size_t)(k*12+e)*NB + b] : 0.f;
    ((unsigned short*)(ws + F_T16H))[i2] = rne_bf16(x);
  }
}

// ---- kVS: fused v_posed (MFMA) + T-blend (MFMA) + skin.
//      7 mB-tiles per block (49 = 7x7 exact); per-g fragments preloaded once;
//      W stage double-buffered, pipelined one tile ahead -> 3 barriers/tile.
__global__ __launch_bounds__(256) void kVS(const float* __restrict__ ws,
    const float* __restrict__ wgt, float* __restrict__ out){
  const unsigned short* Ah = (const unsigned short*)(ws + F_AH);
  const unsigned short* Al = (const unsigned short*)(ws + F_AL);
  const unsigned short* Bh = (const unsigned short*)(ws + F_BTH);
  const unsigned short* Th = (const unsigned short*)(ws + F_T16H);
  __shared__ unsigned short sW[2][1280];   // double-buffered W (hi 0..640, lo 640..1280)
  __shared__ float T_lds[16*196];
  __shared__ float s_out[16*49];

  int t = threadIdx.x;
  int lane = t & 63, wv = t >> 6;
  int c16 = lane & 15, kg = lane >> 4;
  int g  = blockIdx.x;
  int b0 = g*16;
  int tile0 = blockIdx.y*7;

  // per-g preloads (reused for all 7 tiles)
  const short8* pb_h = (const short8*)&Ah[((size_t)g*5) << 9];
  const short8* pb_l = (const short8*)&Al[((size_t)g*5) << 9];
  short8 bh_r[5], bl_r[5];
  #pragma unroll
  for (int ks=0; ks<5; ++ks){
    bh_r[ks] = pb_h[ks*64 + lane];
    bl_r[ks] = pb_l[ks*64 + lane];
  }
  short8 ath[3];
  #pragma unroll
  for (int tt=0; tt<3; ++tt){
    int col = (wv*3+tt)*16 + c16;
    ath[tt] = *(const short8*)&Th[(size_t)g*6144 + col*32 + kg*8];
  }

  // K-pad zeros (invariant) for both buffers, once
  if (t < 128){
    int m = t >> 3, q = t & 7;
    ((unsigned*)sW[0])[m*20 + 8 + q] = 0u;
    ((unsigned*)sW[0])[320 + m*20 + 8 + q] = 0u;
    ((unsigned*)sW[1])[m*20 + 8 + q] = 0u;
    ((unsigned*)sW[1])[320 + m*20 + 8 + q] = 0u;
  }
  // prologue: stage W for tile0 into buf 0
  { int m = t >> 4, j = t & 15;
    int mB = tile0*16;
    float wval = ((mB+m)<MESH) ? wgt[(mB+m)*16 + j] : 0.f;
    unsigned short h = rne_bf16(wval);
    sW[0][m*40 + j] = h;
    sW[0][640 + m*40 + j] = rne_bf16(wval - bf16f(h));
  }

  #pragma unroll 1
  for (int it=0; it<7; ++it){
    int tile = tile0 + it;
    int mB = tile*16;
    int cur = it & 1;

    // stage NEXT tile's W into buf cur^1 (consumed next iteration; latency
    // hides under this tile's MFMA chain)
    if (it < 6){
      int m = t >> 4, j = t & 15;
      int mBn = (tile+1)*16;
      float wval = ((mBn+m)<MESH) ? wgt[(mBn+m)*16 + j] : 0.f;
      unsigned short h = rne_bf16(wval);
      sW[cur^1][m*40 + j] = h;
      sW[cur^1][640 + m*40 + j] = rne_bf16(wval - bf16f(h));
    }

    // ---- vp GEMM: B hi-only x preloaded pose split ----
    int tileA = tile*4 + wv;
    const short8* pa_h = (const short8*)&Bh[((size_t)tileA*5) << 9];
    f32x4 accV = {0.f,0.f,0.f,0.f};
    #pragma unroll
    for (int ks=0; ks<5; ++ks){
      short8 ah = pa_h[ks*64 + lane];
      accV = __builtin_amdgcn_mfma_f32_16x16x32_bf16(ah, bh_r[ks], accV, 0, 0, 0);
      accV = __builtin_amdgcn_mfma_f32_16x16x32_bf16(ah, bl_r[ks], accV, 0, 0, 0);
    }
    __syncthreads();   // B1: sW[cur] ready; prior iter's T_lds/s_out consumers done

    // ---- T blend: (Wh+Wl) x T16h ----
    short8 wh = *(const short8*)&sW[cur][c16*40 + kg*8];
    short8 wl = *(const short8*)&sW[cur][640 + c16*40 + kg*8];
    #pragma unroll
    for (int tt=0; tt<3; ++tt){
      int col = (wv*3+tt)*16 + c16;
      f32x4 accT = {0.f,0.f,0.f,0.f};
      accT = __builtin_amdgcn_mfma_f32_16x16x32_bf16(wh, ath[tt], accT, 0, 0, 0);
      accT = __builtin_amdgcn_mfma_f32_16x16x32_bf16(wl, ath[tt], accT, 0, 0, 0);
      #pragma unroll
      for (int r=0;r<4;++r)
        T_lds[(kg*4+r)*196 + col] = accT[r];
    }
    __syncthreads();   // B2

    // ---- apply ----
    int ml = wv*4 + kg;
    int m  = mB + ml;
    int b  = b0 + c16;
    float4 t0 = *(const float4*)&T_lds[ml*196 + c16*12 + 0];
    float4 t1 = *(const float4*)&T_lds[ml*196 + c16*12 + 4];
    float4 t2 = *(const float4*)&T_lds[ml*196 + c16*12 + 8];
    float vx = accV[0], vy = accV[1], vz = accV[2];
    float r0 = t0.x*vx + t0.y*vy + t0.z*vz + t0.w;
    float r1 = t1.x*vx + t1.y*vy + t1.z*vz + t1.w;
    float r2 = t2.x*vx + t2.y*vy + t2.z*vz + t2.w;
    s_out[c16*49 + ml*3 + 0] = r0;
    s_out[c16*49 + ml*3 + 1] = r1;
    s_out[c16*49 + ml*3 + 2] = r2;
    if (m==333 || m==444 || m==672 || m==555 || m==745){
      int kt = (m==333)?4:(m==444)?8:(m==672)?12:(m==555)?16:20;
      int base = JOUT + b*63 + kt*3;
      out[base+0]=r0; out[base+1]=r1; out[base+2]=r2;
    }
    __syncthreads();   // B3

    // ---- coalesced vertex write-out ----
    for (int idx=t; idx<16*48; idx+=256){
      int i = idx/48, r = idx - i*48;
      if (mB + r/3 < MESH)
        out[(size_t)(b0+i)*(MESH*3) + mB*3 + r] = s_out[i*49 + r];
    }
  }
}

// ================= fallback (proven round-4 fused kernel) =================
__global__ __launch_bounds__(256) void kM_fb(const float* __restrict__ root,
    const float* __restrict__ other, const float* __restrict__ bet,
    const float* __restrict__ vt, const float* __restrict__ sd,
    const float* __restrict__ pd, const float* __restrict__ wgt,
    const float* __restrict__ hc, const float* __restrict__ hm,
    const float* __restrict__ ws, float* __restrict__ out){
  __shared__ float s_pw[32*140];
  __shared__ float s_big[16*408];
  __shared__ float s_vp[32*51];
  __shared__ float s_betas[32*12];
  __shared__ float s_sd[16*30];
  __shared__ float s_vt[48];
  __shared__ float s_w[256];
  __shared__ float s_rot[32*12];
  __shared__ float s_oth[32*6];
  __shared__ float s_js[528];

  int t = threadIdx.x;
  int m0 = blockIdx.x*16;
  int b0 = blockIdx.y*32;

  for (int idx=t; idx<16*408; idx+=256){
    int m = idx/408, r = idx - m*408;
    int c = r/136, p = r - c*136;
    float v = 0.f;
    if (p < 135 && (m0+m) < MESH) v = pd[((size_t)(m0+m)*3+c)*135 + p];
    s_big[m*408 + c*136 + p] = v;
  }
  for (int idx=t; idx<32*10; idx+=256){
    int i = idx/10, k = idx - i*10;
    s_betas[i*12+k] = bet[(b0+i)*10+k];
  }
  for (int idx=t; idx<16*30; idx+=256){
    int m = idx/30, r = idx - m*30;
    s_sd[m*30+r] = ((m0+m)<MESH) ? sd[(m0+m)*30 + r] : 0.f;
  }
  for (int idx=t; idx<48; idx+=256){
    int m = idx/3;
    s_vt[idx] = ((m0+m)<MESH) ? vt[m0*3 + idx] : 0.f;
  }
  for (int idx=t; idx<256; idx+=256){
    int m = idx/16;
    s_w[idx] = ((m0+m)<MESH) ? wgt[m0*16 + idx] : 0.f;
  }
  for (int idx=t; idx<192; idx+=256) s_oth[idx] = other[(size_t)b0*6 + idx];
  for (int idx=t; idx<528; idx+=256) s_js[idx] = ws[idx];
  __syncthreads();

  for (int task=t; task<512; task+=256){
    if (task < 480){
      int b = task/15, jj = task - b*15;
      int q0 = jj*3;
      float rx=hm[q0], ry=hm[q0+1], rz=hm[q0+2];
      #pragma unroll
      for (int u=0;u<6;++u){
        float o = s_oth[b*6+u];
        rx += o*hc[u*45+q0+0];
        ry += o*hc[u*45+q0+1];
        rz += o*hc[u*45+q0+2];
      }
      float Rl[9]; rodrigues(rx,ry,rz,Rl);
      float* pw = &s_pw[b*140 + jj*9];
      pw[0]=Rl[0]-1.f; pw[1]=Rl[1];     pw[2]=Rl[2];
      pw[3]=Rl[3];     pw[4]=Rl[4]-1.f; pw[5]=Rl[5];
      pw[6]=Rl[6];     pw[7]=Rl[7];     pw[8]=Rl[8]-1.f;
    } else {
      int b = task-480;
      float Rr[9];
      rodrigues(root[(b0+b)*3+0], root[(b0+b)*3+1], root[(b0+b)*3+2], Rr);
      #pragma unroll
      for (int e=0;e<9;++e) s_rot[b*12+e] = Rr[e];
      s_pw[b*140 + 135] = 0.f;
    }
  }
  __syncthreads();

  int bl = t & 31, mg = t >> 5;
  float acc[2][3];
  #pragma unroll
  for (int mi=0; mi<2; ++mi){
    int ml = mg*2+mi;
    #pragma unroll
    for (int c=0; c<3; ++c){
      float a = s_vt[ml*3+c];
      #pragma unroll
      for (int k=0;k<10;++k) a += s_betas[bl*12+k]*s_sd[ml*30+c*10+k];
      acc[mi][c]=a;
    }
  }
  const float4* pwv = reinterpret_cast<const float4*>(&s_pw[bl*140]);
  #pragma unroll 2
  for (int pq=0; pq<34; ++pq){
    float4 w = pwv[pq];
    #pragma unroll
    for (int mi=0; mi<2; ++mi){
      int ml = mg*2+mi;
      #pragma unroll
      for (int c=0;c<3;++c){
        float4 d = *reinterpret_cast<const float4*>(&s_big[ml*408 + c*136 + pq*4]);
        acc[mi][c] += w.x*d.x + w.y*d.y + w.z*d.z + w.w*d.w;
      }
    }
  }
  #pragma unroll
  for (int mi=0;mi<2;++mi){
    int ml=mg*2+mi;
    #pragma unroll
    for (int c=0;c<3;++c) s_vp[bl*51+ml*3+c] = acc[mi][c];
  }
  __syncthreads();

  if (t < 160){
    int b = t/5, ch = t - b*5;
    int gb = b0 + b;
    float bt_[10];
    #pragma unroll
    for (int k=0;k<10;++k) bt_[k] = s_betas[b*12+k];
    float R0[9]; rodrigues(PI_F, 0.f, 0.f, R0);
    float J0[3];
    #pragma unroll
    for (int c=0;c<3;++c){
      float a = s_js[c*11 + 10];
      #pragma unroll
      for (int k=0;k<10;++k) a += bt_[k]*s_js[c*11 + k];
      J0[c]=a;
    }
    float Rot[9];
    #pragma unroll
    for (int e=0;e<9;++e) Rot[e] = s_rot[b*12+e];
    if (ch == 0){
      #pragma unroll
      for (int r=0;r<3;++r){
        float tr = J0[r];
        #pragma unroll
        for (int d=0;d<3;++d) tr -= R0[r*3+d]*J0[d];
        s_big[(r*4+0)*33 + b] = R0[r*3+0];
        s_big[(r*4+1)*33 + b] = R0[r*3+1];
        s_big[(r*4+2)*33 + b] = R0[r*3+2];
        s_big[(r*4+3)*33 + b] = tr;
      }
      if (blockIdx.x == 0){
        int base = JOUT + gb*63;
        #pragma unroll
        for (int c=0;c<3;++c)
          out[base+c] = Rot[c*3+0]*J0[0]+Rot[c*3+1]*J0[1]+Rot[c*3+2]*J0[2];
      }
    }
    float GpR[9], Gpt[3], Jp[3];
    #pragma unroll
    for (int e=0;e<9;++e) GpR[e]=R0[e];
    #pragma unroll
    for (int c=0;c<3;++c){ Gpt[c]=J0[c]; Jp[c]=J0[c]; }
    int start = 1 + ch*3;
    #pragma unroll 1
    for (int s=0;s<3;++s){
      int i = start+s;
      float Rl[9];
      #pragma unroll
      for (int e=0;e<9;++e){
        float v = s_pw[b*140 + (i-1)*9 + e];
        Rl[e] = (e==0||e==4||e==8) ? v+1.f : v;
      }
      float Ji[3];
      #pragma unroll
      for (int c=0;c<3;++c){
        float a = s_js[i*33 + c*11 + 10];
        #pragma unroll
        for (int k=0;k<10;++k) a += bt_[k]*s_js[i*33 + c*11 + k];
        Ji[c]=a;
      }
      float tl[3] = {Ji[0]-Jp[0], Ji[1]-Jp[1], Ji[2]-Jp[2]};
      float GR[9], Gt[3];
      #pragma unroll
      for (int r=0;r<3;++r){
        #pragma unroll
        for (int cc=0;cc<3;++cc)
          GR[r*3+cc] = GpR[r*3+0]*Rl[0*3+cc] + GpR[r*3+1]*Rl[1*3+cc] + GpR[r*3+2]*Rl[2*3+cc];
        Gt[r] = Gpt[r] + GpR[r*3+0]*tl[0] + GpR[r*3+1]*tl[1] + GpR[r*3+2]*tl[2];
      }
      #pragma unroll
      for (int r=0;r<3;++r){
        float tr = Gt[r] - (GR[r*3+0]*Ji[0] + GR[r*3+1]*Ji[1] + GR[r*3+2]*Ji[2]);
        s_big[(i*12 + r*4+0)*33 + b] = GR[r*3+0];
        s_big[(i*12 + r*4+1)*33 + b] = GR[r*3+1];
        s_big[(i*12 + r*4+2)*33 + b] = GR[r*3+2];
        s_big[(i*12 + r*4+3)*33 + b] = tr;
      }
      if (blockIdx.x == 0){
        int gx = i + (i>=4) + (i>=7) + (i>=10) + (i>=13);
        int base = JOUT + gb*63 + gx*3;
        #pragma unroll
        for (int c=0;c<3;++c)
          out[base+c] = Rot[c*3+0]*Gt[0]+Rot[c*3+1]*Gt[1]+Rot[c*3+2]*Gt[2];
      }
      #pragma unroll
      for (int e=0;e<9;++e) GpR[e]=GR[e];
      #pragma unroll
      for (int c=0;c<3;++c){ Gpt[c]=Gt[c]; Jp[c]=Ji[c]; }
    }
  }
  __syncthreads();

  #pragma unroll
  for (int mi=0;mi<2;++mi){
    int ml = mg*2+mi; int m = m0+ml;
    float T[12];
    #pragma unroll
    for (int e=0;e<12;++e) T[e]=0.f;
    #pragma unroll
    for (int j=0;j<16;++j){
      float wj = s_w[ml*16+j];
      #pragma unroll
      for (int e=0;e<12;++e) T[e] += wj * s_big[(j*12+e)*33 + bl];
    }
    float vx = s_vp[bl*51+ml*3+0];
    float vy = s_vp[bl*51+ml*3+1];
    float vz = s_vp[bl*51+ml*3+2];
    float v0 = T[0]*vx+T[1]*vy+T[2]*vz+T[3];
    float v1 = T[4]*vx+T[5]*vy+T[6]*vz+T[7];
    float v2 = T[8]*vx+T[9]*vy+T[10]*vz+T[11];
    float r0 = s_rot[bl*12+0]*v0 + s_rot[bl*12+1]*v1 + s_rot[bl*12+2]*v2;
    float r1 = s_rot[bl*12+3]*v0 + s_rot[bl*12+4]*v1 + s_rot[bl*12+5]*v2;
    float r2 = s_rot[bl*12+6]*v0 + s_rot[bl*12+7]*v1 + s_rot[bl*12+8]*v2;
    s_pw[bl*49 + ml*3 + 0] = r0;
    s_pw[bl*49 + ml*3 + 1] = r1;
    s_pw[bl*49 + ml*3 + 2] = r2;
    if (m==333 || m==444 || m==672 || m==555 || m==745){
      int kt = (m==333)?4:(m==444)?8:(m==672)?12:(m==555)?16:20;
      int base = JOUT + (b0+bl)*63 + kt*3;
      out[base+0]=r0; out[base+1]=r1; out[base+2]=r2;
    }
  }
  __syncthreads();

  for (int idx=t; idx<32*48; idx+=256){
    int i = idx/48, r = idx - i*48;
    if (m0 + r/3 < MESH)
      out[(size_t)(b0+i)*(MESH*3) + m0*3 + r] = s_pw[i*49 + r];
  }
}

extern "C" void kernel_launch(void* const* d_in, const int* in_sizes, int n_in,
                              void* d_out, int out_size, void* d_ws, size_t ws_size,
                              hipStream_t stream) {
  const float* root  = (const float*)d_in[0];
  const float* other = (const float*)d_in[1];
  const float* bet   = (const float*)d_in[2];
  const float* vt    = (const float*)d_in[3];
  const float* sd    = (const float*)d_in[4];
  const float* pdirs = (const float*)d_in[5];
  const float* jreg  = (const float*)d_in[6];
  const float* wgt   = (const float*)d_in[7];
  const float* hc    = (const float*)d_in[8];
  const float* hm    = (const float*)d_in[9];
  float* ws = (float*)d_ws;
  float* out = (float*)d_out;

  if (ws_size >= WS_NEED_BYTES){
    kJP<<<dim3(528 + (NPP*160+255)/256), dim3(256), 0, stream>>>(vt, sd, pdirs, jreg, ws);
    kB<<<dim3(16, 5), dim3(256), 0, stream>>>(root, other, bet, hc, hm, ws, out);
    kT<<<dim3((NB*160 + NGRP*6144 + 255)/256), dim3(256), 0, stream>>>(ws);
    kVS<<<dim3(NGRP, 7), dim3(256), 0, stream>>>(ws, wgt, out);
  } else {
    kJP<<<dim3(528), dim3(256), 0, stream>>>(vt, sd, pdirs, jreg, ws);
    kM_fb<<<dim3(49, 128), dim3(256), 0, stream>>>(root, other, bet, vt, sd, pdirs,
                                                   wgt, hc, hm, ws, out);
  }
}

// Round 25
// 54.554 us; speedup vs baseline: 1.0048x; 1.0048x over previous
//
#include <hip/hip_runtime.h>
#include <hip/hip_bf16.h>

#define NB 4096
#define NGRP 256                 // NB/16 batch groups
#define MESH 778
#define NPP 3136                 // padded N: 4 rows (x,y,z,pad) per vertex
#define JOUT (NB*MESH*3)
#define PI_F 3.14159265358979323846f

// ws layout (float offsets).
// Bh fragment-major u16 (hi only); Ah/Al fragment-major u16 (pose rows, split).
// T16h u16 (hi only): [g][col=i16*12+e][k=j(0..15), pad 16..31].
// Pw f32 [160 k][NB]; Af f32 [192 e][NB] (Rot-folded).
#define F_JS   0
#define F_PW   528
#define F_AF   (F_PW + 160*NB)
#define F_AH   (F_AF + 192*NB)
#define F_AL   (F_AH + 80*NB)
#define F_BTH  (F_AL + 80*NB)
#define F_BTL  (F_BTH + NPP*80)          // unused (layout stability)
#define F_T16H (F_BTL + NPP*80)
#define F_T16L (F_T16H + NGRP*3072)      // unused
#define WS_NEED_BYTES ((size_t)(F_T16L + NGRP*3072 + 64) * 4)

typedef __attribute__((ext_vector_type(8))) short short8;
typedef __attribute__((ext_vector_type(4))) float f32x4;

__device__ __forceinline__ unsigned short rne_bf16(float x){
  unsigned u = __float_as_uint(x);
  return (unsigned short)((u + 0x7FFFu + ((u>>16)&1u)) >> 16);
}
__device__ __forceinline__ float bf16f(unsigned short h){
  return __uint_as_float(((unsigned)h)<<16);
}

__device__ __forceinline__ void rodrigues(float x, float y, float z, float* R){
  float t2 = x*x + y*y + z*z;
  float th = sqrtf(t2);
  if (th < 1e-30f){
    float a = 1.0f - t2*(1.0f/6.0f);
    float b = 0.5f - t2*(1.0f/24.0f);
    R[0] = 1.0f + b*(x*x - t2); R[1] = -a*z + b*x*y;       R[2] = a*y + b*x*z;
    R[3] = a*z + b*x*y;         R[4] = 1.0f + b*(y*y - t2); R[5] = -a*x + b*y*z;
    R[6] = -a*y + b*x*z;        R[7] = a*x + b*y*z;        R[8] = 1.0f + b*(z*z - t2);
  } else {
    float inv = 1.0f / fmaxf(th, 1e-12f);
    float nx = x*inv, ny = y*inv, nz = z*inv;
    float s = sinf(th), c = cosf(th), ic = 1.0f - c;
    R[0] = c + ic*nx*nx;    R[1] = ic*nx*ny - s*nz; R[2] = ic*nx*nz + s*ny;
    R[3] = ic*ny*nx + s*nz; R[4] = c + ic*ny*ny;    R[5] = ic*ny*nz - s*nx;
    R[6] = ic*nz*nx - s*ny; R[7] = ic*nz*ny + s*nx; R[8] = c + ic*nz*nz;
  }
}

// ---- kJP: wide kJ (blocks 0..527, one (j,combo) each) + B^T-hi build (blocks 528..)
__global__ __launch_bounds__(256) void kJP(const float* __restrict__ vt,
    const float* __restrict__ sd, const float* __restrict__ pd,
    const float* __restrict__ jreg, float* __restrict__ ws){
  __shared__ float s_part[4];
  if (blockIdx.x < 528){
    int j = blockIdx.x / 33, combo = blockIdx.x - j*33;
    int c = combo / 11, k = combo - c*11;
    float acc = 0.f;
    for (int m = threadIdx.x; m < MESH; m += 256){
      float jr = jreg[j*MESH + m];
      float x = (k < 10) ? sd[(m*3 + c)*10 + k] : vt[m*3 + c];
      acc += jr * x;
    }
    #pragma unroll
    for (int off = 32; off; off >>= 1) acc += __shfl_down(acc, off, 64);
    int lane = threadIdx.x & 63, w = threadIdx.x >> 6;
    if (lane == 0) s_part[w] = acc;
    __syncthreads();
    if (threadIdx.x == 0)
      ws[j*33 + combo] = s_part[0]+s_part[1]+s_part[2]+s_part[3];
  } else {
    int idx = (blockIdx.x-528)*256 + threadIdx.x;
    if (idx >= NPP*160) return;
    int chunk = idx >> 9, q = idx & 511;
    int ln = q >> 3, e = q & 7;
    int tile = chunk/5, ks = chunk - tile*5;
    int c16 = ln & 15, kg = ln >> 4;
    int np = tile*16 + c16;
    int k  = ks*32 + kg*8 + e;
    int m = np >> 2, c = np & 3;
    float x = 0.f;
    if (c < 3 && m < MESH){
      int row = m*3 + c;
      if (k < 135) x = pd[(size_t)row*135 + k];
      else if (k < 145) x = sd[row*10 + (k-135)];
      else if (k == 145) x = vt[row];
    }
    ((unsigned short*)(ws + F_BTH))[idx] = rne_bf16(x);
  }
}

// ---- kB: chain-parallel pose pipeline; ALL writes coalesced f32 transposed.
__global__ __launch_bounds__(256) void kB(const float* __restrict__ root,
    const float* __restrict__ other, const float* __restrict__ bet,
    const float* __restrict__ hc, const float* __restrict__ hm,
    float* __restrict__ ws, float* __restrict__ out){
  int b = blockIdx.x*256 + threadIdx.x;
  if (b >= NB) return;
  int ch = blockIdx.y;
  float* Pw = ws + F_PW;
  float* Af = ws + F_AF;

  float o[6];
  #pragma unroll
  for (int u=0;u<6;++u) o[u] = other[b*6+u];
  float bt[10];
  #pragma unroll
  for (int k=0;k<10;++k) bt[k] = bet[b*10+k];
  float Rot[9];
  rodrigues(root[b*3+0], root[b*3+1], root[b*3+2], Rot);
  float R0[9];
  rodrigues(PI_F, 0.f, 0.f, R0);
  float J0[3];
  #pragma unroll
  for (int c=0;c<3;++c){
    float a = ws[c*11 + 10];
    #pragma unroll
    for (int k=0;k<10;++k) a += bt[k]*ws[c*11 + k];
    J0[c]=a;
  }
  if (ch == 0){
    #pragma unroll
    for (int k=135;k<160;++k)
      Pw[(size_t)k*NB + b] = (k < 145) ? bt[k-135] : (k == 145 ? 1.0f : 0.f);
    float tr0[3];
    #pragma unroll
    for (int r=0;r<3;++r){
      float tr = J0[r];
      #pragma unroll
      for (int d=0;d<3;++d) tr -= R0[r*3+d]*J0[d];
      tr0[r]=tr;
    }
    #pragma unroll
    for (int r=0;r<3;++r)
      #pragma unroll
      for (int cc=0;cc<4;++cc){
        float v = 0.f;
        #pragma unroll
        for (int d=0;d<3;++d) v += Rot[r*3+d]*((cc<3)? R0[d*3+cc] : tr0[d]);
        Af[(size_t)(r*4+cc)*NB + b] = v;
      }
    int base = JOUT + b*63;
    #pragma unroll
    for (int c=0;c<3;++c)
      out[base+c] = Rot[c*3+0]*J0[0]+Rot[c*3+1]*J0[1]+Rot[c*3+2]*J0[2];
  }
  float GpR[9], Gpt[3], Jp[3];
  #pragma unroll
  for (int e=0;e<9;++e) GpR[e]=R0[e];
  #pragma unroll
  for (int c=0;c<3;++c){ Gpt[c]=J0[c]; Jp[c]=J0[c]; }
  int start = 1 + ch*3;
  #pragma unroll 1
  for (int s=0;s<3;++s){
    int i = start+s;
    int q0 = (i-1)*3;
    float rx=hm[q0], ry=hm[q0+1], rz=hm[q0+2];
    #pragma unroll
    for (int u=0;u<6;++u){
      rx += o[u]*hc[u*45+q0+0];
      ry += o[u]*hc[u*45+q0+1];
      rz += o[u]*hc[u*45+q0+2];
    }
    float Rl[9]; rodrigues(rx,ry,rz,Rl);
    #pragma unroll
    for (int e=0;e<9;++e){
      float v = (e==0||e==4||e==8) ? Rl[e]-1.f : Rl[e];
      Pw[(size_t)((i-1)*9+e)*NB + b] = v;
    }
    float Ji[3];
    #pragma unroll
    for (int c=0;c<3;++c){
      float a = ws[i*33 + c*11 + 10];
      #pragma unroll
      for (int k=0;k<10;++k) a += bt[k]*ws[i*33 + c*11 + k];
      Ji[c]=a;
    }
    float tl[3] = {Ji[0]-Jp[0], Ji[1]-Jp[1], Ji[2]-Jp[2]};
    float GR[9], Gt[3];
    #pragma unroll
    for (int r=0;r<3;++r){
      #pragma unroll
      for (int cc=0;cc<3;++cc)
        GR[r*3+cc] = GpR[r*3+0]*Rl[0*3+cc] + GpR[r*3+1]*Rl[1*3+cc] + GpR[r*3+2]*Rl[2*3+cc];
      Gt[r] = Gpt[r] + GpR[r*3+0]*tl[0] + GpR[r*3+1]*tl[1] + GpR[r*3+2]*tl[2];
    }
    float trv[3];
    #pragma unroll
    for (int r=0;r<3;++r)
      trv[r] = Gt[r] - (GR[r*3+0]*Ji[0] + GR[r*3+1]*Ji[1] + GR[r*3+2]*Ji[2]);
    #pragma unroll
    for (int r=0;r<3;++r)
      #pragma unroll
      for (int cc=0;cc<4;++cc){
        float v = 0.f;
        #pragma unroll
        for (int d=0;d<3;++d) v += Rot[r*3+d]*((cc<3)? GR[d*3+cc] : trv[d]);
        Af[(size_t)(i*12 + r*4+cc)*NB + b] = v;
      }
    int gx = i + (i>=4) + (i>=7) + (i>=10) + (i>=13);
    int base = JOUT + b*63 + gx*3;
    #pragma unroll
    for (int c=0;c<3;++c)
      out[base+c] = Rot[c*3+0]*Gt[0]+Rot[c*3+1]*Gt[1]+Rot[c*3+2]*Gt[2];
    #pragma unroll
    for (int e=0;e<9;++e) GpR[e]=GR[e];
    #pragma unroll
    for (int c=0;c<3;++c){ Gpt[c]=Gt[c]; Jp[c]=Ji[c]; }
  }
}

// ---- kT: element-parallel converter (linear u16 writes).
__global__ __launch_bounds__(256) void kT(float* __restrict__ ws){
  int idx = blockIdx.x*256 + threadIdx.x;
  const float* Pw = ws + F_PW;
  const float* Af = ws + F_AF;
  if (idx < NB*160){
    int chunk = idx >> 9, q = idx & 511;
    int ln = q >> 3, e = q & 7;
    int tile = chunk/5, ks = chunk - tile*5;
    int c16 = ln & 15, kg = ln >> 4;
    int b = tile*16 + c16;
    int k = ks*32 + kg*8 + e;
    float x = Pw[(size_t)k*NB + b];
    unsigned short h = rne_bf16(x);
    ((unsigned short*)(ws + F_AH))[idx] = h;
    ((unsigned short*)(ws + F_AL))[idx] = rne_bf16(x - bf16f(h));
  } else {
    int i2 = idx - NB*160;
    if (i2 >= NGRP*6144) return;
    int g = i2/6144, r = i2 - g*6144;
    int col = r >> 5, k = r & 31;
    int i16 = col/12, e = col - i16*12;
    int b = g*16 + i16;
    float x = (k < 16) ? Af[(size_t)(k*12+e)*NB + b] : 0.f;
    ((unsigned short*)(ws + F_T16H))[i2] = rne_bf16(x);
  }
}

// ---- kVS: fused v_posed (MFMA) + T-blend (MFMA) + skin.
//      4 mB-tiles per block; per-g fragments preloaded once; W stage
//      double-buffered and pipelined one tile ahead -> 3 barriers/tile,
//      W-load latency hidden under the MFMA chain.
__global__ __launch_bounds__(256) void kVS(const float* __restrict__ ws,
    const float* __restrict__ wgt, float* __restrict__ out){
  const unsigned short* Ah = (const unsigned short*)(ws + F_AH);
  const unsigned short* Al = (const unsigned short*)(ws + F_AL);
  const unsigned short* Bh = (const unsigned short*)(ws + F_BTH);
  const unsigned short* Th = (const unsigned short*)(ws + F_T16H);
  __shared__ unsigned short sW[2][1280];   // double-buffered W (hi 0..640, lo 640..1280)
  __shared__ float T_lds[16*196];
  __shared__ float s_out[16*49];

  int t = threadIdx.x;
  int lane = t & 63, wv = t >> 6;
  int c16 = lane & 15, kg = lane >> 4;
  int g  = blockIdx.x;
  int b0 = g*16;
  int tile0 = blockIdx.y*4;

  // per-g preloads (reused for all 4 tiles)
  const short8* pb_h = (const short8*)&Ah[((size_t)g*5) << 9];
  const short8* pb_l = (const short8*)&Al[((size_t)g*5) << 9];
  short8 bh_r[5], bl_r[5];
  #pragma unroll
  for (int ks=0; ks<5; ++ks){
    bh_r[ks] = pb_h[ks*64 + lane];
    bl_r[ks] = pb_l[ks*64 + lane];
  }
  short8 ath[3];
  #pragma unroll
  for (int tt=0; tt<3; ++tt){
    int col = (wv*3+tt)*16 + c16;
    ath[tt] = *(const short8*)&Th[(size_t)g*6144 + col*32 + kg*8];
  }

  // K-pad zeros (invariant) for both buffers, once
  if (t < 128){
    int m = t >> 3, q = t & 7;
    ((unsigned*)sW[0])[m*20 + 8 + q] = 0u;
    ((unsigned*)sW[0])[320 + m*20 + 8 + q] = 0u;
    ((unsigned*)sW[1])[m*20 + 8 + q] = 0u;
    ((unsigned*)sW[1])[320 + m*20 + 8 + q] = 0u;
  }
  // prologue: stage W for tile0 into buf 0
  { int m = t >> 4, j = t & 15;
    int mB = tile0*16;
    float wval = ((mB+m)<MESH) ? wgt[(mB+m)*16 + j] : 0.f;
    unsigned short h = rne_bf16(wval);
    sW[0][m*40 + j] = h;
    sW[0][640 + m*40 + j] = rne_bf16(wval - bf16f(h));
  }

  #pragma unroll 1
  for (int it=0; it<4; ++it){
    int tile = tile0 + it;
    if (tile >= 49) break;
    int mB = tile*16;
    int cur = it & 1;

    // stage NEXT tile's W into buf cur^1 (consumed next iteration; latency
    // hides under this tile's MFMA chain)
    if (it < 3 && tile+1 < 49){
      int m = t >> 4, j = t & 15;
      int mBn = (tile+1)*16;
      float wval = ((mBn+m)<MESH) ? wgt[(mBn+m)*16 + j] : 0.f;
      unsigned short h = rne_bf16(wval);
      sW[cur^1][m*40 + j] = h;
      sW[cur^1][640 + m*40 + j] = rne_bf16(wval - bf16f(h));
    }

    // ---- vp GEMM: B hi-only x preloaded pose split ----
    int tileA = tile*4 + wv;
    const short8* pa_h = (const short8*)&Bh[((size_t)tileA*5) << 9];
    f32x4 accV = {0.f,0.f,0.f,0.f};
    #pragma unroll
    for (int ks=0; ks<5; ++ks){
      short8 ah = pa_h[ks*64 + lane];
      accV = __builtin_amdgcn_mfma_f32_16x16x32_bf16(ah, bh_r[ks], accV, 0, 0, 0);
      accV = __builtin_amdgcn_mfma_f32_16x16x32_bf16(ah, bl_r[ks], accV, 0, 0, 0);
    }
    __syncthreads();   // B1: sW[cur] ready; prior iter's T_lds/s_out consumers done

    // ---- T blend: (Wh+Wl) x T16h ----
    short8 wh = *(const short8*)&sW[cur][c16*40 + kg*8];
    short8 wl = *(const short8*)&sW[cur][640 + c16*40 + kg*8];
    #pragma unroll
    for (int tt=0; tt<3; ++tt){
      int col = (wv*3+tt)*16 + c16;
      f32x4 accT = {0.f,0.f,0.f,0.f};
      accT = __builtin_amdgcn_mfma_f32_16x16x32_bf16(wh, ath[tt], accT, 0, 0, 0);
      accT = __builtin_amdgcn_mfma_f32_16x16x32_bf16(wl, ath[tt], accT, 0, 0, 0);
      #pragma unroll
      for (int r=0;r<4;++r)
        T_lds[(kg*4+r)*196 + col] = accT[r];
    }
    __syncthreads();   // B2

    // ---- apply ----
    int ml = wv*4 + kg;
    int m  = mB + ml;
    int b  = b0 + c16;
    float4 t0 = *(const float4*)&T_lds[ml*196 + c16*12 + 0];
    float4 t1 = *(const float4*)&T_lds[ml*196 + c16*12 + 4];
    float4 t2 = *(const float4*)&T_lds[ml*196 + c16*12 + 8];
    float vx = accV[0], vy = accV[1], vz = accV[2];
    float r0 = t0.x*vx + t0.y*vy + t0.z*vz + t0.w;
    float r1 = t1.x*vx + t1.y*vy + t1.z*vz + t1.w;
    float r2 = t2.x*vx + t2.y*vy + t2.z*vz + t2.w;
    s_out[c16*49 + ml*3 + 0] = r0;
    s_out[c16*49 + ml*3 + 1] = r1;
    s_out[c16*49 + ml*3 + 2] = r2;
    if (m==333 || m==444 || m==672 || m==555 || m==745){
      int kt = (m==333)?4:(m==444)?8:(m==672)?12:(m==555)?16:20;
      int base = JOUT + b*63 + kt*3;
      out[base+0]=r0; out[base+1]=r1; out[base+2]=r2;
    }
    __syncthreads();   // B3

    // ---- coalesced vertex write-out ----
    for (int idx=t; idx<16*48; idx+=256){
      int i = idx/48, r = idx - i*48;
      if (mB + r/3 < MESH)
        out[(size_t)(b0+i)*(MESH*3) + mB*3 + r] = s_out[i*49 + r];
    }
  }
}

// ================= fallback (proven round-4 fused kernel) =================
__global__ __launch_bounds__(256) void kM_fb(const float* __restrict__ root,
    const float* __restrict__ other, const float* __restrict__ bet,
    const float* __restrict__ vt, const float* __restrict__ sd,
    const float* __restrict__ pd, const float* __restrict__ wgt,
    const float* __restrict__ hc, const float* __restrict__ hm,
    const float* __restrict__ ws, float* __restrict__ out){
  __shared__ float s_pw[32*140];
  __shared__ float s_big[16*408];
  __shared__ float s_vp[32*51];
  __shared__ float s_betas[32*12];
  __shared__ float s_sd[16*30];
  __shared__ float s_vt[48];
  __shared__ float s_w[256];
  __shared__ float s_rot[32*12];
  __shared__ float s_oth[32*6];
  __shared__ float s_js[528];

  int t = threadIdx.x;
  int m0 = blockIdx.x*16;
  int b0 = blockIdx.y*32;

  for (int idx=t; idx<16*408; idx+=256){
    int m = idx/408, r = idx - m*408;
    int c = r/136, p = r - c*136;
    float v = 0.f;
    if (p < 135 && (m0+m) < MESH) v = pd[((size_t)(m0+m)*3+c)*135 + p];
    s_big[m*408 + c*136 + p] = v;
  }
  for (int idx=t; idx<32*10; idx+=256){
    int i = idx/10, k = idx - i*10;
    s_betas[i*12+k] = bet[(b0+i)*10+k];
  }
  for (int idx=t; idx<16*30; idx+=256){
    int m = idx/30, r = idx - m*30;
    s_sd[m*30+r] = ((m0+m)<MESH) ? sd[(m0+m)*30 + r] : 0.f;
  }
  for (int idx=t; idx<48; idx+=256){
    int m = idx/3;
    s_vt[idx] = ((m0+m)<MESH) ? vt[m0*3 + idx] : 0.f;
  }
  for (int idx=t; idx<256; idx+=256){
    int m = idx/16;
    s_w[idx] = ((m0+m)<MESH) ? wgt[m0*16 + idx] : 0.f;
  }
  for (int idx=t; idx<192; idx+=256) s_oth[idx] = other[(size_t)b0*6 + idx];
  for (int idx=t; idx<528; idx+=256) s_js[idx] = ws[idx];
  __syncthreads();

  for (int task=t; task<512; task+=256){
    if (task < 480){
      int b = task/15, jj = task - b*15;
      int q0 = jj*3;
      float rx=hm[q0], ry=hm[q0+1], rz=hm[q0+2];
      #pragma unroll
      for (int u=0;u<6;++u){
        float o = s_oth[b*6+u];
        rx += o*hc[u*45+q0+0];
        ry += o*hc[u*45+q0+1];
        rz += o*hc[u*45+q0+2];
      }
      float Rl[9]; rodrigues(rx,ry,rz,Rl);
      float* pw = &s_pw[b*140 + jj*9];
      pw[0]=Rl[0]-1.f; pw[1]=Rl[1];     pw[2]=Rl[2];
      pw[3]=Rl[3];     pw[4]=Rl[4]-1.f; pw[5]=Rl[5];
      pw[6]=Rl[6];     pw[7]=Rl[7];     pw[8]=Rl[8]-1.f;
    } else {
      int b = task-480;
      float Rr[9];
      rodrigues(root[(b0+b)*3+0], root[(b0+b)*3+1], root[(b0+b)*3+2], Rr);
      #pragma unroll
      for (int e=0;e<9;++e) s_rot[b*12+e] = Rr[e];
      s_pw[b*140 + 135] = 0.f;
    }
  }
  __syncthreads();

  int bl = t & 31, mg = t >> 5;
  float acc[2][3];
  #pragma unroll
  for (int mi=0; mi<2; ++mi){
    int ml = mg*2+mi;
    #pragma unroll
    for (int c=0; c<3; ++c){
      float a = s_vt[ml*3+c];
      #pragma unroll
      for (int k=0;k<10;++k) a += s_betas[bl*12+k]*s_sd[ml*30+c*10+k];
      acc[mi][c]=a;
    }
  }
  const float4* pwv = reinterpret_cast<const float4*>(&s_pw[bl*140]);
  #pragma unroll 2
  for (int pq=0; pq<34; ++pq){
    float4 w = pwv[pq];
    #pragma unroll
    for (int mi=0; mi<2; ++mi){
      int ml = mg*2+mi;
      #pragma unroll
      for (int c=0;c<3;++c){
        float4 d = *reinterpret_cast<const float4*>(&s_big[ml*408 + c*136 + pq*4]);
        acc[mi][c] += w.x*d.x + w.y*d.y + w.z*d.z + w.w*d.w;
      }
    }
  }
  #pragma unroll
  for (int mi=0;mi<2;++mi){
    int ml=mg*2+mi;
    #pragma unroll
    for (int c=0;c<3;++c) s_vp[bl*51+ml*3+c] = acc[mi][c];
  }
  __syncthreads();

  if (t < 160){
    int b = t/5, ch = t - b*5;
    int gb = b0 + b;
    float bt_[10];
    #pragma unroll
    for (int k=0;k<10;++k) bt_[k] = s_betas[b*12+k];
    float R0[9]; rodrigues(PI_F, 0.f, 0.f, R0);
    float J0[3];
    #pragma unroll
    for (int c=0;c<3;++c){
      float a = s_js[c*11 + 10];
      #pragma unroll
      for (int k=0;k<10;++k) a += bt_[k]*s_js[c*11 + k];
      J0[c]=a;
    }
    float Rot[9];
    #pragma unroll
    for (int e=0;e<9;++e) Rot[e] = s_rot[b*12+e];
    if (ch == 0){
      #pragma unroll
      for (int r=0;r<3;++r){
        float tr = J0[r];
        #pragma unroll
        for (int d=0;d<3;++d) tr -= R0[r*3+d]*J0[d];
        s_big[(r*4+0)*33 + b] = R0[r*3+0];
        s_big[(r*4+1)*33 + b] = R0[r*3+1];
        s_big[(r*4+2)*33 + b] = R0[r*3+2];
        s_big[(r*4+3)*33 + b] = tr;
      }
      if (blockIdx.x == 0){
        int base = JOUT + gb*63;
        #pragma unroll
        for (int c=0;c<3;++c)
          out[base+c] = Rot[c*3+0]*J0[0]+Rot[c*3+1]*J0[1]+Rot[c*3+2]*J0[2];
      }
    }
    float GpR[9], Gpt[3], Jp[3];
    #pragma unroll
    for (int e=0;e<9;++e) GpR[e]=R0[e];
    #pragma unroll
    for (int c=0;c<3;++c){ Gpt[c]=J0[c]; Jp[c]=J0[c]; }
    int start = 1 + ch*3;
    #pragma unroll 1
    for (int s=0;s<3;++s){
      int i = start+s;
      float Rl[9];
      #pragma unroll
      for (int e=0;e<9;++e){
        float v = s_pw[b*140 + (i-1)*9 + e];
        Rl[e] = (e==0||e==4||e==8) ? v+1.f : v;
      }
      float Ji[3];
      #pragma unroll
      for (int c=0;c<3;++c){
        float a = s_js[i*33 + c*11 + 10];
        #pragma unroll
        for (int k=0;k<10;++k) a += bt_[k]*s_js[i*33 + c*11 + k];
        Ji[c]=a;
      }
      float tl[3] = {Ji[0]-Jp[0], Ji[1]-Jp[1], Ji[2]-Jp[2]};
      float GR[9], Gt[3];
      #pragma unroll
      for (int r=0;r<3;++r){
        #pragma unroll
        for (int cc=0;cc<3;++cc)
          GR[r*3+cc] = GpR[r*3+0]*Rl[0*3+cc] + GpR[r*3+1]*Rl[1*3+cc] + GpR[r*3+2]*Rl[2*3+cc];
        Gt[r] = Gpt[r] + GpR[r*3+0]*tl[0] + GpR[r*3+1]*tl[1] + GpR[r*3+2]*tl[2];
      }
      #pragma unroll
      for (int r=0;r<3;++r){
        float tr = Gt[r] - (GR[r*3+0]*Ji[0] + GR[r*3+1]*Ji[1] + GR[r*3+2]*Ji[2]);
        s_big[(i*12 + r*4+0)*33 + b] = GR[r*3+0];
        s_big[(i*12 + r*4+1)*33 + b] = GR[r*3+1];
        s_big[(i*12 + r*4+2)*33 + b] = GR[r*3+2];
        s_big[(i*12 + r*4+3)*33 + b] = tr;
      }
      if (blockIdx.x == 0){
        int gx = i + (i>=4) + (i>=7) + (i>=10) + (i>=13);
        int base = JOUT + gb*63 + gx*3;
        #pragma unroll
        for (int c=0;c<3;++c)
          out[base+c] = Rot[c*3+0]*Gt[0]+Rot[c*3+1]*Gt[1]+Rot[c*3+2]*Gt[2];
      }
      #pragma unroll
      for (int e=0;e<9;++e) GpR[e]=GR[e];
      #pragma unroll
      for (int c=0;c<3;++c){ Gpt[c]=Gt[c]; Jp[c]=Ji[c]; }
    }
  }
  __syncthreads();

  #pragma unroll
  for (int mi=0;mi<2;++mi){
    int ml = mg*2+mi; int m = m0+ml;
    float T[12];
    #pragma unroll
    for (int e=0;e<12;++e) T[e]=0.f;
    #pragma unroll
    for (int j=0;j<16;++j){
      float wj = s_w[ml*16+j];
      #pragma unroll
      for (int e=0;e<12;++e) T[e] += wj * s_big[(j*12+e)*33 + bl];
    }
    float vx = s_vp[bl*51+ml*3+0];
    float vy = s_vp[bl*51+ml*3+1];
    float vz = s_vp[bl*51+ml*3+2];
    float v0 = T[0]*vx+T[1]*vy+T[2]*vz+T[3];
    float v1 = T[4]*vx+T[5]*vy+T[6]*vz+T[7];
    float v2 = T[8]*vx+T[9]*vy+T[10]*vz+T[11];
    float r0 = s_rot[bl*12+0]*v0 + s_rot[bl*12+1]*v1 + s_rot[bl*12+2]*v2;
    float r1 = s_rot[bl*12+3]*v0 + s_rot[bl*12+4]*v1 + s_rot[bl*12+5]*v2;
    float r2 = s_rot[bl*12+6]*v0 + s_rot[bl*12+7]*v1 + s_rot[bl*12+8]*v2;
    s_pw[bl*49 + ml*3 + 0] = r0;
    s_pw[bl*49 + ml*3 + 1] = r1;
    s_pw[bl*49 + ml*3 + 2] = r2;
    if (m==333 || m==444 || m==672 || m==555 || m==745){
      int kt = (m==333)?4:(m==444)?8:(m==672)?12:(m==555)?16:20;
      int base = JOUT + (b0+bl)*63 + kt*3;
      out[base+0]=r0; out[base+1]=r1; out[base+2]=r2;
    }
  }
  __syncthreads();

  for (int idx=t; idx<32*48; idx+=256){
    int i = idx/48, r = idx - i*48;
    if (m0 + r/3 < MESH)
      out[(size_t)(b0+i)*(MESH*3) + m0*3 + r] = s_pw[i*49 + r];
  }
}

extern "C" void kernel_launch(void* const* d_in, const int* in_sizes, int n_in,
                              void* d_out, int out_size, void* d_ws, size_t ws_size,
                              hipStream_t stream) {
  const float* root  = (const float*)d_in[0];
  const float* other = (const float*)d_in[1];
  const float* bet   = (const float*)d_in[2];
  const float* vt    = (const float*)d_in[3];
  const float* sd    = (const float*)d_in[4];
  const float* pdirs = (const float*)d_in[5];
  const float* jreg  = (const float*)d_in[6];
  const float* wgt   = (const float*)d_in[7];
  const float* hc    = (const float*)d_in[8];
  const float* hm    = (const float*)d_in[9];
  float* ws = (float*)d_ws;
  float* out = (float*)d_out;

  if (ws_size >= WS_NEED_BYTES){
    kJP<<<dim3(528 + (NPP*160+255)/256), dim3(256), 0, stream>>>(vt, sd, pdirs, jreg, ws);
    kB<<<dim3(16, 5), dim3(256), 0, stream>>>(root, other, bet, hc, hm, ws, out);
    kT<<<dim3((NB*160 + NGRP*6144 + 255)/256), dim3(256), 0, stream>>>(ws);
    kVS<<<dim3(NGRP, 13), dim3(256), 0, stream>>>(ws, wgt, out);
  } else {
    kJP<<<dim3(528), dim3(256), 0, stream>>>(vt, sd, pdirs, jreg, ws);
    kM_fb<<<dim3(49, 128), dim3(256), 0, stream>>>(root, other, bet, vt, sd, pdirs,
                                                   wgt, hc, hm, ws, out);
  }
}